// Round 3
// baseline (2496.018 us; speedup 1.0000x reference)
//
#include <hip/hip_runtime.h>
#include <hip/hip_bf16.h>

#define B_ 4
#define N_ 4096
#define NS_ 1024
#define KNN_ 32
#define NPOS_ 131072   /* B_*NS_*KNN_ */
#define BN_EPS_ 1e-5f

using bf16 = __hip_bfloat16;

__device__ __forceinline__ float bf2f(bf16 h){ return __bfloat162float(h); }
__device__ __forceinline__ unsigned short f2bfbits(float x){
    bf16 h = __float2bfloat16(x);
    return *reinterpret_cast<unsigned short*>(&h);
}
__device__ __forceinline__ void unpack8(uint4 v, float* f){
    f[0]=__uint_as_float((v.x&0xFFFFu)<<16); f[1]=__uint_as_float(v.x&0xFFFF0000u);
    f[2]=__uint_as_float((v.y&0xFFFFu)<<16); f[3]=__uint_as_float(v.y&0xFFFF0000u);
    f[4]=__uint_as_float((v.z&0xFFFFu)<<16); f[5]=__uint_as_float(v.z&0xFFFF0000u);
    f[6]=__uint_as_float((v.w&0xFFFFu)<<16); f[7]=__uint_as_float(v.w&0xFFFF0000u);
}
__device__ __forceinline__ uint4 pack8(const float* f){
    uint4 v;
    v.x = (unsigned)f2bfbits(f[0]) | ((unsigned)f2bfbits(f[1])<<16);
    v.y = (unsigned)f2bfbits(f[2]) | ((unsigned)f2bfbits(f[3])<<16);
    v.z = (unsigned)f2bfbits(f[4]) | ((unsigned)f2bfbits(f[5])<<16);
    v.w = (unsigned)f2bfbits(f[6]) | ((unsigned)f2bfbits(f[7])<<16);
    return v;
}
// monotone map: unsigned compare == float compare (handles negatives)
__device__ __forceinline__ unsigned fmono(float v){
    unsigned u = __float_as_uint(v);
    return (u & 0x80000000u) ? ~u : (u | 0x80000000u);
}

// -------------------- zero stats --------------------
__global__ void zero_stats(float* s){ s[blockIdx.x*256 + threadIdx.x] = 0.0f; }

// -------------------- W26 = w2 @ w1  (256x6, stored [j][c]) --------------------
__global__ __launch_bounds__(256) void prep_w26(const float* __restrict__ w1,
                                                const float* __restrict__ w2,
                                                float* __restrict__ W26){
    int c = threadIdx.x;
    float acc[6] = {0,0,0,0,0,0};
    for (int k=0;k<256;k++){
        float w2v = w2[c*256+k];
        #pragma unroll
        for (int j=0;j<6;j++) acc[j] = fmaf(w2v, w1[k*6+j], acc[j]);
    }
    #pragma unroll
    for (int j=0;j<6;j++) W26[j*256+c] = acc[j];
}

// -------------------- FPS: 1 block per batch --------------------
__global__ __launch_bounds__(1024) void fps_kernel(const float* __restrict__ p,
                                                   int* __restrict__ idxc,
                                                   float* __restrict__ cntrd){
    __shared__ float px[N_], py[N_], pz[N_];
    __shared__ unsigned long long warr[16];
    const int b = blockIdx.x;
    const int t = threadIdx.x;
    const float* pb = p + (size_t)b*N_*3;
    float rx[4], ry[4], rz[4], dist[4];
    #pragma unroll
    for (int j=0;j<4;j++){
        int i = t*4+j;
        float x = pb[i*3+0];
        float y = pb[i*3+1];
        float z = pb[i*3+2];
        rx[j]=x; ry[j]=y; rz[j]=z;
        px[i]=x; py[i]=y; pz[i]=z;
        dist[j]=1e10f;
    }
    __syncthreads();
    int cur = 0;
    if (t==0){
        idxc[b*NS_] = 0;
        cntrd[(size_t)(b*NS_)*3+0] = px[0];
        cntrd[(size_t)(b*NS_)*3+1] = py[0];
        cntrd[(size_t)(b*NS_)*3+2] = pz[0];
    }
    for (int s=1; s<NS_; s++){
        float cx = px[cur], cy = py[cur], cz = pz[cur];
        unsigned long long best = 0ull;
        #pragma unroll
        for (int j=0;j<4;j++){
            float dx = __fsub_rn(rx[j],cx);
            float dy = __fsub_rn(ry[j],cy);
            float dz = __fsub_rn(rz[j],cz);
            float d  = __fadd_rn(__fadd_rn(__fmul_rn(dx,dx),__fmul_rn(dy,dy)),__fmul_rn(dz,dz));
            float dm = fminf(dist[j], d);
            dist[j] = dm;
            unsigned long long key = ((unsigned long long)__float_as_uint(dm)<<32)
                                   | (unsigned)(0xFFFFFFFFu - (unsigned)(t*4+j));
            best = best > key ? best : key;
        }
        #pragma unroll
        for (int m=1;m<64;m<<=1){
            unsigned long long o = __shfl_xor(best, m, 64);
            best = best > o ? best : o;
        }
        if ((t&63)==0) warr[t>>6] = best;
        __syncthreads();
        unsigned long long g = warr[0];
        #pragma unroll
        for (int w=1;w<16;w++){ unsigned long long o = warr[w]; g = g > o ? g : o; }
        cur = (int)(0xFFFFFFFFu - (unsigned)(g & 0xFFFFFFFFull));
        if (t==0){
            idxc[b*NS_+s] = cur;
            cntrd[(size_t)(b*NS_+s)*3+0] = px[cur];
            cntrd[(size_t)(b*NS_+s)*3+1] = py[cur];
            cntrd[(size_t)(b*NS_+s)*3+2] = pz[cur];
        }
        __syncthreads();
    }
}

// -------------------- KNN: 1 block (256 thr) per centroid --------------------
__global__ __launch_bounds__(256) void knn_kernel(const float* __restrict__ p,
                                                  const int* __restrict__ idxc,
                                                  int* __restrict__ knn){
    __shared__ unsigned long long warr[4];
    const int bid = blockIdx.x;          // b*NS_+s
    const int b = bid >> 10;
    const int t = threadIdx.x;
    const float* pb = p + (size_t)b*N_*3;
    const int ci = idxc[bid];
    float cx = pb[ci*3+0];
    float cy = pb[ci*3+1];
    float cz = pb[ci*3+2];
    float c2 = __fadd_rn(__fadd_rn(__fmul_rn(cx,cx),__fmul_rn(cy,cy)),__fmul_rn(cz,cz));
    float d2[16];
    const int base = t*16;
    #pragma unroll
    for (int j=0;j<16;j++){
        int i = base+j;
        float x = pb[i*3+0];
        float y = pb[i*3+1];
        float z = pb[i*3+2];
        float p2 = __fadd_rn(__fadd_rn(__fmul_rn(x,x),__fmul_rn(y,y)),__fmul_rn(z,z));
        float dot= __fadd_rn(__fadd_rn(__fmul_rn(cx,x),__fmul_rn(cy,y)),__fmul_rn(cz,z));
        d2[j] = __fsub_rn(__fadd_rn(c2,p2), __fmul_rn(2.0f,dot));
    }
    for (int it=0; it<KNN_; it++){
        unsigned long long best = ~0ull;
        #pragma unroll
        for (int j=0;j<16;j++){
            unsigned long long key = ((unsigned long long)fmono(d2[j])<<32) | (unsigned)(base+j);
            best = best < key ? best : key;
        }
        #pragma unroll
        for (int m=1;m<64;m<<=1){
            unsigned long long o = __shfl_xor(best, m, 64);
            best = best < o ? best : o;
        }
        if ((t&63)==0) warr[t>>6] = best;
        __syncthreads();
        unsigned long long g = warr[0];
        #pragma unroll
        for (int w=1;w<4;w++){ unsigned long long o = warr[w]; g = g < o ? g : o; }
        int idx = (int)(g & 0xFFFFFFFFull);
        if ((idx>>4)==t) d2[idx & 15] = INFINITY;
        if (t==0) knn[(size_t)bid*KNN_ + it] = idx;
        __syncthreads();
    }
}

// -------------------- gather + conv1 + conv2 (+b2) -> z2 bf16 [256][NPOS] ------
__global__ __launch_bounds__(256) void conv12_kernel(const float* __restrict__ p,
                                                     const float* __restrict__ f,
                                                     const int* __restrict__ knn,
                                                     const float* __restrict__ W26,
                                                     const float* __restrict__ b2,
                                                     bf16* __restrict__ z2){
    __shared__ float Ws[6][256];
    __shared__ float xs[6][32];
    const int bid = blockIdx.x;          // b*NS_+s
    const int b = bid >> 10;
    const int t = threadIdx.x;
    #pragma unroll
    for (int r=0;r<6;r++) Ws[r][t] = W26[r*256+t];
    if (t < 32){
        int i = knn[(size_t)bid*KNN_ + t];
        const float* pb = p + (size_t)b*N_*3;
        const float* fb = f + (size_t)b*3*N_;
        xs[0][t] = pb[i*3+0];
        xs[1][t] = pb[i*3+1];
        xs[2][t] = pb[i*3+2];
        xs[3][t] = fb[0*N_+i];
        xs[4][t] = fb[1*N_+i];
        xs[5][t] = fb[2*N_+i];
    }
    __syncthreads();
    float w0=Ws[0][t], w1v=Ws[1][t], w2v=Ws[2][t], w3v=Ws[3][t], w4v=Ws[4][t], w5v=Ws[5][t];
    float bias = b2[t];
    bf16* zrow = z2 + (size_t)t*NPOS_ + (size_t)bid*KNN_;
    for (int k0=0;k0<32;k0+=8){
        float y[8];
        #pragma unroll
        for (int u=0;u<8;u++){
            int k = k0+u;
            float acc = bias;
            acc = fmaf(w0, xs[0][k], acc);
            acc = fmaf(w1v,xs[1][k], acc);
            acc = fmaf(w2v,xs[2][k], acc);
            acc = fmaf(w3v,xs[3][k], acc);
            acc = fmaf(w4v,xs[4][k], acc);
            acc = fmaf(w5v,xs[5][k], acc);
            y[u] = acc;
        }
        *reinterpret_cast<uint4*>(zrow + k0) = pack8(y);
    }
}

// -------------------- BN stats: sums[c*2]=sum, sums[c*2+1]=sumsq --------------
__global__ __launch_bounds__(256) void stats_kernel(const bf16* __restrict__ z,
                                                    float* __restrict__ sums){
    __shared__ float sw[4], qw[4];
    const int c = blockIdx.y;
    const int chunk = blockIdx.x;
    const int t = threadIdx.x;
    const bf16* zp = z + (size_t)c*NPOS_ + (size_t)chunk*16384;
    const uint4* zp4 = reinterpret_cast<const uint4*>(zp);
    float s=0.f, q=0.f;
    for (int r=0;r<8;r++){
        uint4 v = zp4[r*256 + t];
        float fv[8]; unpack8(v, fv);
        #pragma unroll
        for (int u=0;u<8;u++){ s += fv[u]; q = fmaf(fv[u], fv[u], q); }
    }
    #pragma unroll
    for (int m=1;m<64;m<<=1){ s += __shfl_xor(s,m,64); q += __shfl_xor(q,m,64); }
    if ((t&63)==0){ sw[t>>6]=s; qw[t>>6]=q; }
    __syncthreads();
    if (t==0){
        s = sw[0]+sw[1]+sw[2]+sw[3];
        q = qw[0]+qw[1]+qw[2]+qw[3];
        atomicAdd(&sums[c*2+0], s);
        atomicAdd(&sums[c*2+1], q);
    }
}

// -------------------- BN normalize + ReLU in-place --------------------
__global__ __launch_bounds__(256) void norm_kernel(bf16* __restrict__ z,
                                                   const float* __restrict__ sums,
                                                   const float* __restrict__ g,
                                                   const float* __restrict__ be){
    const int c = blockIdx.y;
    const int chunk = blockIdx.x;
    const int t = threadIdx.x;
    const float inv = 1.0f/(float)NPOS_;
    float mean = sums[c*2+0]*inv;
    float var  = sums[c*2+1]*inv - mean*mean;
    float rs = rsqrtf(var + BN_EPS_);
    float a  = g[c]*rs;
    float bb = be[c] - mean*a;
    bf16* zp = z + (size_t)c*NPOS_ + (size_t)chunk*16384;
    uint4* zp4 = reinterpret_cast<uint4*>(zp);
    for (int r=0;r<8;r++){
        uint4 v = zp4[r*256 + t];
        float fv[8]; unpack8(v, fv);
        #pragma unroll
        for (int u=0;u<8;u++) fv[u] = fmaxf(fmaf(fv[u], a, bb), 0.0f);
        zp4[r*256 + t] = pack8(fv);
    }
}

// -------------------- xm = max over K (per c, per bs) --------------------
__global__ __launch_bounds__(256) void xm_kernel(const bf16* __restrict__ x2n,
                                                 bf16* __restrict__ xm){
    int gid = blockIdx.x*256 + threadIdx.x;  // c*4096 + bs
    int c = gid >> 12;
    int bs = gid & 4095;
    const uint4* xp = reinterpret_cast<const uint4*>(x2n + (size_t)c*NPOS_ + (size_t)bs*KNN_);
    float m = -INFINITY;
    #pragma unroll
    for (int r=0;r<4;r++){
        uint4 v = xp[r];
        float fv[8]; unpack8(v, fv);
        #pragma unroll
        for (int u=0;u<8;u++) m = fmaxf(m, fv[u]);
    }
    xm[(size_t)c*4096 + bs] = __float2bfloat16(m);
}

// -------------------- tiled GEMM: out[M][N] = A[M][lda](+aoff) * B[K][N] ------
// A is f32 (weights); B is bf16 (activations).
// Cb: bf16 out (or null), Cf: f32 out (or null), Tadd: f32 [M][N>>5] (or null)
__global__ __launch_bounds__(256) void gemm128(const float* __restrict__ A, int lda, int aoff,
                                               const bf16* __restrict__ B,
                                               int M, int N, int K,
                                               bf16* __restrict__ Cb,
                                               float* __restrict__ Cf,
                                               const float* __restrict__ Tadd){
    __shared__ float As[16][128];
    __shared__ float Bs[16][128];
    const int tid = threadIdx.x;
    const int tx = tid & 15, ty = tid >> 4;
    const int m0 = blockIdx.y*128, n0 = blockIdx.x*128;
    float acc[8][8];
    #pragma unroll
    for (int i=0;i<8;i++)
        #pragma unroll
        for (int j=0;j<8;j++) acc[i][j]=0.f;

    const int arow = tid >> 1, akg = tid & 1;
    const int bkk = tid >> 4, bng = tid & 15;

    for (int k0=0;k0<K;k0+=16){
        const float* aptr = A + (size_t)(m0+arow)*lda + aoff + k0 + akg*8;
        float4 a0 = *reinterpret_cast<const float4*>(aptr);
        float4 a1 = *reinterpret_cast<const float4*>(aptr+4);
        As[akg*8+0][arow]=a0.x; As[akg*8+1][arow]=a0.y;
        As[akg*8+2][arow]=a0.z; As[akg*8+3][arow]=a0.w;
        As[akg*8+4][arow]=a1.x; As[akg*8+5][arow]=a1.y;
        As[akg*8+6][arow]=a1.z; As[akg*8+7][arow]=a1.w;
        uint4 bv = *reinterpret_cast<const uint4*>(B + (size_t)(k0+bkk)*N + n0 + bng*8);
        float bf[8]; unpack8(bv, bf);
        *reinterpret_cast<float4*>(&Bs[bkk][bng*8+0]) = make_float4(bf[0],bf[1],bf[2],bf[3]);
        *reinterpret_cast<float4*>(&Bs[bkk][bng*8+4]) = make_float4(bf[4],bf[5],bf[6],bf[7]);
        __syncthreads();
        #pragma unroll
        for (int kk=0;kk<16;kk++){
            float a[8], b[8];
            *reinterpret_cast<float4*>(&a[0]) = *reinterpret_cast<float4*>(&As[kk][ty*8+0]);
            *reinterpret_cast<float4*>(&a[4]) = *reinterpret_cast<float4*>(&As[kk][ty*8+4]);
            *reinterpret_cast<float4*>(&b[0]) = *reinterpret_cast<float4*>(&Bs[kk][tx*8+0]);
            *reinterpret_cast<float4*>(&b[4]) = *reinterpret_cast<float4*>(&Bs[kk][tx*8+4]);
            #pragma unroll
            for (int i=0;i<8;i++)
                #pragma unroll
                for (int j=0;j<8;j++)
                    acc[i][j] = fmaf(a[i], b[j], acc[i][j]);
        }
        __syncthreads();
    }
    const int n = n0 + tx*8;
    const int ldT = N >> 5;
    const int bsj = n >> 5;
    #pragma unroll
    for (int i=0;i<8;i++){
        int m = m0 + ty*8 + i;
        float tadd = Tadd ? Tadd[(size_t)m*ldT + bsj] : 0.0f;
        float row[8];
        #pragma unroll
        for (int j=0;j<8;j++) row[j] = acc[i][j] + tadd;
        if (Cb){
            *reinterpret_cast<uint4*>(Cb + (size_t)m*N + n) = pack8(row);
        } else {
            *reinterpret_cast<float4*>(Cf + (size_t)m*N + n + 0) = make_float4(row[0],row[1],row[2],row[3]);
            *reinterpret_cast<float4*>(Cf + (size_t)m*N + n + 4) = make_float4(row[4],row[5],row[6],row[7]);
        }
    }
}

// -------------------- final: BN + ReLU + maxpool over K -> out (f32) ---------
__global__ __launch_bounds__(256) void final_kernel(const bf16* __restrict__ z4,
                                                    const float* __restrict__ sums,
                                                    const float* __restrict__ g,
                                                    const float* __restrict__ be,
                                                    float* __restrict__ out){
    int gid = blockIdx.x*256 + threadIdx.x;   // b(2b) | c(8b) | s(10b)
    int s = gid & 1023;
    int c = (gid >> 10) & 255;
    int b = gid >> 18;
    int bsi = b*NS_ + s;
    const float inv = 1.0f/(float)NPOS_;
    float mean = sums[c*2+0]*inv;
    float var  = sums[c*2+1]*inv - mean*mean;
    float rs = rsqrtf(var + BN_EPS_);
    float a  = g[c]*rs;
    float bb = be[c] - mean*a;
    const uint4* zp = reinterpret_cast<const uint4*>(z4 + (size_t)c*NPOS_ + (size_t)bsi*KNN_);
    float m = -INFINITY;
    #pragma unroll
    for (int r=0;r<4;r++){
        uint4 v = zp[r];
        float fv[8]; unpack8(v, fv);
        #pragma unroll
        for (int u=0;u<8;u++) m = fmaxf(m, fmaf(fv[u], a, bb));
    }
    m = fmaxf(m, 0.0f);   // ReLU commutes with max
    out[(size_t)(b*256 + c)*NS_ + s] = m;
}

extern "C" void kernel_launch(void* const* d_in, const int* in_sizes, int n_in,
                              void* d_out, int out_size, void* d_ws, size_t ws_size,
                              hipStream_t stream) {
    const float* p   = (const float*)d_in[0];
    const float* f   = (const float*)d_in[1];
    const float* w1  = (const float*)d_in[2];
    const float* w2  = (const float*)d_in[3];
    const float* b2  = (const float*)d_in[4];
    const float* g2  = (const float*)d_in[5];
    const float* be2 = (const float*)d_in[6];
    const float* w3  = (const float*)d_in[7];
    const float* g3  = (const float*)d_in[8];
    const float* be3 = (const float*)d_in[9];
    const float* w4  = (const float*)d_in[10];
    const float* g4  = (const float*)d_in[11];
    const float* be4 = (const float*)d_in[12];

    // Workspace layout: total 212,367,360 B (~202.5 MB); z4 aliases z2.
    char* ws = (char*)d_ws;
    int*   idxc  = (int*)(ws + 0);            // 16 KB
    int*   knn   = (int*)(ws + 16384);        // 512 KB
    float* W26   = (float*)(ws + 540672);     // 6 KB
    float* stats = (float*)(ws + 546816);     // 8 KB (2048 floats)
    float* t3    = (float*)(ws + 555008);     // 8 MB
    bf16*  z2    = (bf16*)(ws + 8943616);     // 64 MB  (reused as z4)
    bf16*  xm    = (bf16*)(ws + 76052480);    // 2 MB
    bf16*  z3    = (bf16*)(ws + 78149632);    // 128 MB (end 212367360)
    bf16*  z4    = z2;                        // alias

    float* out_cntrd = (float*)d_out;
    float* out_feat  = (float*)d_out + (size_t)B_*NS_*3;

    zero_stats<<<8, 256, 0, stream>>>(stats);
    prep_w26<<<1, 256, 0, stream>>>(w1, w2, W26);
    fps_kernel<<<B_, 1024, 0, stream>>>(p, idxc, out_cntrd);
    knn_kernel<<<B_*NS_, 256, 0, stream>>>(p, idxc, knn);
    conv12_kernel<<<B_*NS_, 256, 0, stream>>>(p, f, knn, W26, b2, z2);
    stats_kernel<<<dim3(8,256), 256, 0, stream>>>(z2, stats);
    norm_kernel<<<dim3(8,256), 256, 0, stream>>>(z2, stats, g2, be2);
    xm_kernel<<<4096, 256, 0, stream>>>(z2, xm);
    // t3[o][bs] = w3[:, :256] @ xm
    gemm128<<<dim3(32,4), 256, 0, stream>>>(w3, 512, 0,   xm, 512, 4096,   256, nullptr, t3, nullptr);
    // z3 = w3[:, 256:] @ x2n + t3(broadcast over k)
    gemm128<<<dim3(1024,4), 256, 0, stream>>>(w3, 512, 256, z2, 512, 131072, 256, z3, nullptr, t3);
    stats_kernel<<<dim3(8,512), 256, 0, stream>>>(z3, stats + 512);
    norm_kernel<<<dim3(8,512), 256, 0, stream>>>(z3, stats + 512, g3, be3);
    // z4 = w4 @ x3   (z4 aliases z2; z2 dead from here on)
    gemm128<<<dim3(1024,2), 256, 0, stream>>>(w4, 512, 0, z3, 256, 131072, 512, z4, nullptr, nullptr);
    stats_kernel<<<dim3(8,256), 256, 0, stream>>>(z4, stats + 1536);
    final_kernel<<<4096, 256, 0, stream>>>(z4, stats + 1536, g4, be4, out_feat);
}

// Round 4
// 1996.858 us; speedup vs baseline: 1.2500x; 1.2500x over previous
//
#include <hip/hip_runtime.h>
#include <hip/hip_bf16.h>

#define B_ 4
#define N_ 4096
#define NS_ 1024
#define KNN_ 32
#define NPOS_ 131072   /* B_*NS_*KNN_ */
#define BN_EPS_ 1e-5f

using bf16 = __hip_bfloat16;

__device__ __forceinline__ float bf2f(bf16 h){ return __bfloat162float(h); }
__device__ __forceinline__ unsigned short f2bfbits(float x){
    bf16 h = __float2bfloat16(x);
    return *reinterpret_cast<unsigned short*>(&h);
}
__device__ __forceinline__ void unpack8(uint4 v, float* f){
    f[0]=__uint_as_float((v.x&0xFFFFu)<<16); f[1]=__uint_as_float(v.x&0xFFFF0000u);
    f[2]=__uint_as_float((v.y&0xFFFFu)<<16); f[3]=__uint_as_float(v.y&0xFFFF0000u);
    f[4]=__uint_as_float((v.z&0xFFFFu)<<16); f[5]=__uint_as_float(v.z&0xFFFF0000u);
    f[6]=__uint_as_float((v.w&0xFFFFu)<<16); f[7]=__uint_as_float(v.w&0xFFFF0000u);
}
__device__ __forceinline__ uint4 pack8(const float* f){
    uint4 v;
    v.x = (unsigned)f2bfbits(f[0]) | ((unsigned)f2bfbits(f[1])<<16);
    v.y = (unsigned)f2bfbits(f[2]) | ((unsigned)f2bfbits(f[3])<<16);
    v.z = (unsigned)f2bfbits(f[4]) | ((unsigned)f2bfbits(f[5])<<16);
    v.w = (unsigned)f2bfbits(f[6]) | ((unsigned)f2bfbits(f[7])<<16);
    return v;
}
// monotone map: unsigned compare == float compare (handles negatives)
__device__ __forceinline__ unsigned fmono(float v){
    unsigned u = __float_as_uint(v);
    return (u & 0x80000000u) ? ~u : (u | 0x80000000u);
}

// -------------------- zero stats --------------------
__global__ void zero_stats(float* s){ s[blockIdx.x*256 + threadIdx.x] = 0.0f; }

// -------------------- W26 = w2 @ w1  (256x6, stored [j][c]) --------------------
__global__ __launch_bounds__(256) void prep_w26(const float* __restrict__ w1,
                                                const float* __restrict__ w2,
                                                float* __restrict__ W26){
    int c = threadIdx.x;
    float acc[6] = {0,0,0,0,0,0};
    for (int k=0;k<256;k++){
        float w2v = w2[c*256+k];
        #pragma unroll
        for (int j=0;j<6;j++) acc[j] = fmaf(w2v, w1[k*6+j], acc[j]);
    }
    #pragma unroll
    for (int j=0;j<6;j++) W26[j*256+c] = acc[j];
}

// -------------------- FPS: 1 block per batch, 512 thr, 8 pts/thr --------------
// Latency-optimized: per-thread scalar argmax first, single packed-u64 key per
// thread, 6-step wave shuffle, 8-entry cross-wave tail, ONE barrier/iter
// (warr double-buffered by parity; px/py/pz are read-only).
__global__ __launch_bounds__(512) void fps_kernel(const float* __restrict__ p,
                                                  int* __restrict__ idxc,
                                                  float* __restrict__ cntrd){
    __shared__ float px[N_], py[N_], pz[N_];
    __shared__ unsigned long long warr[2][8];
    const int b = blockIdx.x;
    const int t = threadIdx.x;
    const float* pb = p + (size_t)b*N_*3;
    float rx[8], ry[8], rz[8], dist[8];
    #pragma unroll
    for (int j=0;j<8;j++){
        int i = t*8+j;
        float x = pb[i*3+0];
        float y = pb[i*3+1];
        float z = pb[i*3+2];
        rx[j]=x; ry[j]=y; rz[j]=z;
        px[i]=x; py[i]=y; pz[i]=z;
        dist[j]=1e10f;
    }
    __syncthreads();
    int cur = 0;
    if (t==0){
        idxc[b*NS_] = 0;
        cntrd[(size_t)(b*NS_)*3+0] = px[0];
        cntrd[(size_t)(b*NS_)*3+1] = py[0];
        cntrd[(size_t)(b*NS_)*3+2] = pz[0];
    }
    const unsigned invbase = 0xFFFFFFFFu - (unsigned)(t*8);
    for (int s=1; s<NS_; s++){
        float cx = px[cur], cy = py[cur], cz = pz[cur];
        // local min-update + strict-> argmax (keeps first index, matches np)
        float best = -1.0f; int bj = 0;
        #pragma unroll
        for (int j=0;j<8;j++){
            float dx = __fsub_rn(rx[j],cx);
            float dy = __fsub_rn(ry[j],cy);
            float dz = __fsub_rn(rz[j],cz);
            float d  = __fadd_rn(__fadd_rn(__fmul_rn(dx,dx),__fmul_rn(dy,dy)),__fmul_rn(dz,dz));
            float dm = fminf(dist[j], d);
            dist[j] = dm;
            bool gt = dm > best;
            best = gt ? dm : best;
            bj   = gt ? j  : bj;
        }
        // dm >= 0 so raw f32 bits compare monotonically as u32
        unsigned long long key = ((unsigned long long)__float_as_uint(best)<<32)
                               | (unsigned)(invbase - (unsigned)bj);
        #pragma unroll
        for (int m=1;m<64;m<<=1){
            unsigned long long o = __shfl_xor(key, m, 64);
            key = key > o ? key : o;
        }
        if ((t&63)==0) warr[s&1][t>>6] = key;
        __syncthreads();
        unsigned long long g = warr[s&1][0];
        #pragma unroll
        for (int w=1;w<8;w++){ unsigned long long o = warr[s&1][w]; g = g > o ? g : o; }
        cur = (int)(0xFFFFFFFFu - (unsigned)(g & 0xFFFFFFFFull));
        if (t==0){
            idxc[b*NS_+s] = cur;
            cntrd[(size_t)(b*NS_+s)*3+0] = px[cur];
            cntrd[(size_t)(b*NS_+s)*3+1] = py[cur];
            cntrd[(size_t)(b*NS_+s)*3+2] = pz[cur];
        }
        // no second barrier: warr is parity double-buffered
    }
}

// -------------------- KNN: 1 block (256 thr) per centroid --------------------
__global__ __launch_bounds__(256) void knn_kernel(const float* __restrict__ p,
                                                  const int* __restrict__ idxc,
                                                  int* __restrict__ knn){
    __shared__ unsigned long long warr[4];
    const int bid = blockIdx.x;          // b*NS_+s
    const int b = bid >> 10;
    const int t = threadIdx.x;
    const float* pb = p + (size_t)b*N_*3;
    const int ci = idxc[bid];
    float cx = pb[ci*3+0];
    float cy = pb[ci*3+1];
    float cz = pb[ci*3+2];
    float c2 = __fadd_rn(__fadd_rn(__fmul_rn(cx,cx),__fmul_rn(cy,cy)),__fmul_rn(cz,cz));
    float d2[16];
    const int base = t*16;
    #pragma unroll
    for (int j=0;j<16;j++){
        int i = base+j;
        float x = pb[i*3+0];
        float y = pb[i*3+1];
        float z = pb[i*3+2];
        float p2 = __fadd_rn(__fadd_rn(__fmul_rn(x,x),__fmul_rn(y,y)),__fmul_rn(z,z));
        float dot= __fadd_rn(__fadd_rn(__fmul_rn(cx,x),__fmul_rn(cy,y)),__fmul_rn(cz,z));
        d2[j] = __fsub_rn(__fadd_rn(c2,p2), __fmul_rn(2.0f,dot));
    }
    for (int it=0; it<KNN_; it++){
        unsigned long long best = ~0ull;
        #pragma unroll
        for (int j=0;j<16;j++){
            unsigned long long key = ((unsigned long long)fmono(d2[j])<<32) | (unsigned)(base+j);
            best = best < key ? best : key;
        }
        #pragma unroll
        for (int m=1;m<64;m<<=1){
            unsigned long long o = __shfl_xor(best, m, 64);
            best = best < o ? best : o;
        }
        if ((t&63)==0) warr[t>>6] = best;
        __syncthreads();
        unsigned long long g = warr[0];
        #pragma unroll
        for (int w=1;w<4;w++){ unsigned long long o = warr[w]; g = g < o ? g : o; }
        int idx = (int)(g & 0xFFFFFFFFull);
        if ((idx>>4)==t) d2[idx & 15] = INFINITY;
        if (t==0) knn[(size_t)bid*KNN_ + it] = idx;
        __syncthreads();
    }
}

// -------------------- gather + conv1 + conv2 (+b2) -> z2 bf16 [256][NPOS] ------
__global__ __launch_bounds__(256) void conv12_kernel(const float* __restrict__ p,
                                                     const float* __restrict__ f,
                                                     const int* __restrict__ knn,
                                                     const float* __restrict__ W26,
                                                     const float* __restrict__ b2,
                                                     bf16* __restrict__ z2){
    __shared__ float Ws[6][256];
    __shared__ float xs[6][32];
    const int bid = blockIdx.x;          // b*NS_+s
    const int b = bid >> 10;
    const int t = threadIdx.x;
    #pragma unroll
    for (int r=0;r<6;r++) Ws[r][t] = W26[r*256+t];
    if (t < 32){
        int i = knn[(size_t)bid*KNN_ + t];
        const float* pb = p + (size_t)b*N_*3;
        const float* fb = f + (size_t)b*3*N_;
        xs[0][t] = pb[i*3+0];
        xs[1][t] = pb[i*3+1];
        xs[2][t] = pb[i*3+2];
        xs[3][t] = fb[0*N_+i];
        xs[4][t] = fb[1*N_+i];
        xs[5][t] = fb[2*N_+i];
    }
    __syncthreads();
    float w0=Ws[0][t], w1v=Ws[1][t], w2v=Ws[2][t], w3v=Ws[3][t], w4v=Ws[4][t], w5v=Ws[5][t];
    float bias = b2[t];
    bf16* zrow = z2 + (size_t)t*NPOS_ + (size_t)bid*KNN_;
    for (int k0=0;k0<32;k0+=8){
        float y[8];
        #pragma unroll
        for (int u=0;u<8;u++){
            int k = k0+u;
            float acc = bias;
            acc = fmaf(w0, xs[0][k], acc);
            acc = fmaf(w1v,xs[1][k], acc);
            acc = fmaf(w2v,xs[2][k], acc);
            acc = fmaf(w3v,xs[3][k], acc);
            acc = fmaf(w4v,xs[4][k], acc);
            acc = fmaf(w5v,xs[5][k], acc);
            y[u] = acc;
        }
        *reinterpret_cast<uint4*>(zrow + k0) = pack8(y);
    }
}

// -------------------- BN stats: sums[c*2]=sum, sums[c*2+1]=sumsq --------------
__global__ __launch_bounds__(256) void stats_kernel(const bf16* __restrict__ z,
                                                    float* __restrict__ sums){
    __shared__ float sw[4], qw[4];
    const int c = blockIdx.y;
    const int chunk = blockIdx.x;
    const int t = threadIdx.x;
    const bf16* zp = z + (size_t)c*NPOS_ + (size_t)chunk*16384;
    const uint4* zp4 = reinterpret_cast<const uint4*>(zp);
    float s=0.f, q=0.f;
    for (int r=0;r<8;r++){
        uint4 v = zp4[r*256 + t];
        float fv[8]; unpack8(v, fv);
        #pragma unroll
        for (int u=0;u<8;u++){ s += fv[u]; q = fmaf(fv[u], fv[u], q); }
    }
    #pragma unroll
    for (int m=1;m<64;m<<=1){ s += __shfl_xor(s,m,64); q += __shfl_xor(q,m,64); }
    if ((t&63)==0){ sw[t>>6]=s; qw[t>>6]=q; }
    __syncthreads();
    if (t==0){
        s = sw[0]+sw[1]+sw[2]+sw[3];
        q = qw[0]+qw[1]+qw[2]+qw[3];
        atomicAdd(&sums[c*2+0], s);
        atomicAdd(&sums[c*2+1], q);
    }
}

// -------------------- BN normalize + ReLU in-place --------------------
__global__ __launch_bounds__(256) void norm_kernel(bf16* __restrict__ z,
                                                   const float* __restrict__ sums,
                                                   const float* __restrict__ g,
                                                   const float* __restrict__ be){
    const int c = blockIdx.y;
    const int chunk = blockIdx.x;
    const int t = threadIdx.x;
    const float inv = 1.0f/(float)NPOS_;
    float mean = sums[c*2+0]*inv;
    float var  = sums[c*2+1]*inv - mean*mean;
    float rs = rsqrtf(var + BN_EPS_);
    float a  = g[c]*rs;
    float bb = be[c] - mean*a;
    bf16* zp = z + (size_t)c*NPOS_ + (size_t)chunk*16384;
    uint4* zp4 = reinterpret_cast<uint4*>(zp);
    for (int r=0;r<8;r++){
        uint4 v = zp4[r*256 + t];
        float fv[8]; unpack8(v, fv);
        #pragma unroll
        for (int u=0;u<8;u++) fv[u] = fmaxf(fmaf(fv[u], a, bb), 0.0f);
        zp4[r*256 + t] = pack8(fv);
    }
}

// -------------------- xm = max over K (per c, per bs) --------------------
__global__ __launch_bounds__(256) void xm_kernel(const bf16* __restrict__ x2n,
                                                 bf16* __restrict__ xm){
    int gid = blockIdx.x*256 + threadIdx.x;  // c*4096 + bs
    int c = gid >> 12;
    int bs = gid & 4095;
    const uint4* xp = reinterpret_cast<const uint4*>(x2n + (size_t)c*NPOS_ + (size_t)bs*KNN_);
    float m = -INFINITY;
    #pragma unroll
    for (int r=0;r<4;r++){
        uint4 v = xp[r];
        float fv[8]; unpack8(v, fv);
        #pragma unroll
        for (int u=0;u<8;u++) m = fmaxf(m, fv[u]);
    }
    xm[(size_t)c*4096 + bs] = __float2bfloat16(m);
}

// -------------------- tiled GEMM: out[M][N] = A[M][lda](+aoff) * B[K][N] ------
// A is f32 (weights); B is bf16 (activations).
// Cb: bf16 out (or null), Cf: f32 out (or null), Tadd: f32 [M][N>>5] (or null)
__global__ __launch_bounds__(256) void gemm128(const float* __restrict__ A, int lda, int aoff,
                                               const bf16* __restrict__ B,
                                               int M, int N, int K,
                                               bf16* __restrict__ Cb,
                                               float* __restrict__ Cf,
                                               const float* __restrict__ Tadd){
    __shared__ float As[16][128];
    __shared__ float Bs[16][128];
    const int tid = threadIdx.x;
    const int tx = tid & 15, ty = tid >> 4;
    const int m0 = blockIdx.y*128, n0 = blockIdx.x*128;
    float acc[8][8];
    #pragma unroll
    for (int i=0;i<8;i++)
        #pragma unroll
        for (int j=0;j<8;j++) acc[i][j]=0.f;

    const int arow = tid >> 1, akg = tid & 1;
    const int bkk = tid >> 4, bng = tid & 15;

    for (int k0=0;k0<K;k0+=16){
        const float* aptr = A + (size_t)(m0+arow)*lda + aoff + k0 + akg*8;
        float4 a0 = *reinterpret_cast<const float4*>(aptr);
        float4 a1 = *reinterpret_cast<const float4*>(aptr+4);
        As[akg*8+0][arow]=a0.x; As[akg*8+1][arow]=a0.y;
        As[akg*8+2][arow]=a0.z; As[akg*8+3][arow]=a0.w;
        As[akg*8+4][arow]=a1.x; As[akg*8+5][arow]=a1.y;
        As[akg*8+6][arow]=a1.z; As[akg*8+7][arow]=a1.w;
        uint4 bv = *reinterpret_cast<const uint4*>(B + (size_t)(k0+bkk)*N + n0 + bng*8);
        float bf[8]; unpack8(bv, bf);
        *reinterpret_cast<float4*>(&Bs[bkk][bng*8+0]) = make_float4(bf[0],bf[1],bf[2],bf[3]);
        *reinterpret_cast<float4*>(&Bs[bkk][bng*8+4]) = make_float4(bf[4],bf[5],bf[6],bf[7]);
        __syncthreads();
        #pragma unroll
        for (int kk=0;kk<16;kk++){
            float a[8], b[8];
            *reinterpret_cast<float4*>(&a[0]) = *reinterpret_cast<float4*>(&As[kk][ty*8+0]);
            *reinterpret_cast<float4*>(&a[4]) = *reinterpret_cast<float4*>(&As[kk][ty*8+4]);
            *reinterpret_cast<float4*>(&b[0]) = *reinterpret_cast<float4*>(&Bs[kk][tx*8+0]);
            *reinterpret_cast<float4*>(&b[4]) = *reinterpret_cast<float4*>(&Bs[kk][tx*8+4]);
            #pragma unroll
            for (int i=0;i<8;i++)
                #pragma unroll
                for (int j=0;j<8;j++)
                    acc[i][j] = fmaf(a[i], b[j], acc[i][j]);
        }
        __syncthreads();
    }
    const int n = n0 + tx*8;
    const int ldT = N >> 5;
    const int bsj = n >> 5;
    #pragma unroll
    for (int i=0;i<8;i++){
        int m = m0 + ty*8 + i;
        float tadd = Tadd ? Tadd[(size_t)m*ldT + bsj] : 0.0f;
        float row[8];
        #pragma unroll
        for (int j=0;j<8;j++) row[j] = acc[i][j] + tadd;
        if (Cb){
            *reinterpret_cast<uint4*>(Cb + (size_t)m*N + n) = pack8(row);
        } else {
            *reinterpret_cast<float4*>(Cf + (size_t)m*N + n + 0) = make_float4(row[0],row[1],row[2],row[3]);
            *reinterpret_cast<float4*>(Cf + (size_t)m*N + n + 4) = make_float4(row[4],row[5],row[6],row[7]);
        }
    }
}

// -------------------- final: BN + ReLU + maxpool over K -> out (f32) ---------
__global__ __launch_bounds__(256) void final_kernel(const bf16* __restrict__ z4,
                                                    const float* __restrict__ sums,
                                                    const float* __restrict__ g,
                                                    const float* __restrict__ be,
                                                    float* __restrict__ out){
    int gid = blockIdx.x*256 + threadIdx.x;   // b(2b) | c(8b) | s(10b)
    int s = gid & 1023;
    int c = (gid >> 10) & 255;
    int b = gid >> 18;
    int bsi = b*NS_ + s;
    const float inv = 1.0f/(float)NPOS_;
    float mean = sums[c*2+0]*inv;
    float var  = sums[c*2+1]*inv - mean*mean;
    float rs = rsqrtf(var + BN_EPS_);
    float a  = g[c]*rs;
    float bb = be[c] - mean*a;
    const uint4* zp = reinterpret_cast<const uint4*>(z4 + (size_t)c*NPOS_ + (size_t)bsi*KNN_);
    float m = -INFINITY;
    #pragma unroll
    for (int r=0;r<4;r++){
        uint4 v = zp[r];
        float fv[8]; unpack8(v, fv);
        #pragma unroll
        for (int u=0;u<8;u++) m = fmaxf(m, fmaf(fv[u], a, bb));
    }
    m = fmaxf(m, 0.0f);   // ReLU commutes with max
    out[(size_t)(b*256 + c)*NS_ + s] = m;
}

extern "C" void kernel_launch(void* const* d_in, const int* in_sizes, int n_in,
                              void* d_out, int out_size, void* d_ws, size_t ws_size,
                              hipStream_t stream) {
    const float* p   = (const float*)d_in[0];
    const float* f   = (const float*)d_in[1];
    const float* w1  = (const float*)d_in[2];
    const float* w2  = (const float*)d_in[3];
    const float* b2  = (const float*)d_in[4];
    const float* g2  = (const float*)d_in[5];
    const float* be2 = (const float*)d_in[6];
    const float* w3  = (const float*)d_in[7];
    const float* g3  = (const float*)d_in[8];
    const float* be3 = (const float*)d_in[9];
    const float* w4  = (const float*)d_in[10];
    const float* g4  = (const float*)d_in[11];
    const float* be4 = (const float*)d_in[12];

    // Workspace layout: total 212,367,360 B (~202.5 MB); z4 aliases z2.
    char* ws = (char*)d_ws;
    int*   idxc  = (int*)(ws + 0);            // 16 KB
    int*   knn   = (int*)(ws + 16384);        // 512 KB
    float* W26   = (float*)(ws + 540672);     // 6 KB
    float* stats = (float*)(ws + 546816);     // 8 KB (2048 floats)
    float* t3    = (float*)(ws + 555008);     // 8 MB
    bf16*  z2    = (bf16*)(ws + 8943616);     // 64 MB  (reused as z4)
    bf16*  xm    = (bf16*)(ws + 76052480);    // 2 MB
    bf16*  z3    = (bf16*)(ws + 78149632);    // 128 MB (end 212367360)
    bf16*  z4    = z2;                        // alias

    float* out_cntrd = (float*)d_out;
    float* out_feat  = (float*)d_out + (size_t)B_*NS_*3;

    zero_stats<<<8, 256, 0, stream>>>(stats);
    prep_w26<<<1, 256, 0, stream>>>(w1, w2, W26);
    fps_kernel<<<B_, 512, 0, stream>>>(p, idxc, out_cntrd);
    knn_kernel<<<B_*NS_, 256, 0, stream>>>(p, idxc, knn);
    conv12_kernel<<<B_*NS_, 256, 0, stream>>>(p, f, knn, W26, b2, z2);
    stats_kernel<<<dim3(8,256), 256, 0, stream>>>(z2, stats);
    norm_kernel<<<dim3(8,256), 256, 0, stream>>>(z2, stats, g2, be2);
    xm_kernel<<<4096, 256, 0, stream>>>(z2, xm);
    // t3[o][bs] = w3[:, :256] @ xm
    gemm128<<<dim3(32,4), 256, 0, stream>>>(w3, 512, 0,   xm, 512, 4096,   256, nullptr, t3, nullptr);
    // z3 = w3[:, 256:] @ x2n + t3(broadcast over k)
    gemm128<<<dim3(1024,4), 256, 0, stream>>>(w3, 512, 256, z2, 512, 131072, 256, z3, nullptr, t3);
    stats_kernel<<<dim3(8,512), 256, 0, stream>>>(z3, stats + 512);
    norm_kernel<<<dim3(8,512), 256, 0, stream>>>(z3, stats + 512, g3, be3);
    // z4 = w4 @ x3   (z4 aliases z2; z2 dead from here on)
    gemm128<<<dim3(1024,2), 256, 0, stream>>>(w4, 512, 0, z3, 256, 131072, 512, z4, nullptr, nullptr);
    stats_kernel<<<dim3(8,256), 256, 0, stream>>>(z4, stats + 1536);
    final_kernel<<<4096, 256, 0, stream>>>(z4, stats + 1536, g4, be4, out_feat);
}

// Round 5
// 1404.413 us; speedup vs baseline: 1.7773x; 1.4218x over previous
//
#include <hip/hip_runtime.h>
#include <hip/hip_bf16.h>

#define B_ 4
#define N_ 4096
#define NS_ 1024
#define KNN_ 32
#define NPOS_ 131072   /* B_*NS_*KNN_ */
#define BN_EPS_ 1e-5f

using bf16 = __hip_bfloat16;
typedef __attribute__((ext_vector_type(8))) short short8;
typedef __attribute__((ext_vector_type(4))) float f32x4;

__device__ __forceinline__ float bf2f(bf16 h){ return __bfloat162float(h); }
__device__ __forceinline__ unsigned short f2bfbits(float x){
    bf16 h = __float2bfloat16(x);
    return *reinterpret_cast<unsigned short*>(&h);
}
__device__ __forceinline__ float bits2f(unsigned short u){
    unsigned v = ((unsigned)u)<<16; return __uint_as_float(v);
}
__device__ __forceinline__ void unpack8(uint4 v, float* f){
    f[0]=__uint_as_float((v.x&0xFFFFu)<<16); f[1]=__uint_as_float(v.x&0xFFFF0000u);
    f[2]=__uint_as_float((v.y&0xFFFFu)<<16); f[3]=__uint_as_float(v.y&0xFFFF0000u);
    f[4]=__uint_as_float((v.z&0xFFFFu)<<16); f[5]=__uint_as_float(v.z&0xFFFF0000u);
    f[6]=__uint_as_float((v.w&0xFFFFu)<<16); f[7]=__uint_as_float(v.w&0xFFFF0000u);
}
__device__ __forceinline__ uint4 pack8(const float* f){
    uint4 v;
    v.x = (unsigned)f2bfbits(f[0]) | ((unsigned)f2bfbits(f[1])<<16);
    v.y = (unsigned)f2bfbits(f[2]) | ((unsigned)f2bfbits(f[3])<<16);
    v.z = (unsigned)f2bfbits(f[4]) | ((unsigned)f2bfbits(f[5])<<16);
    v.w = (unsigned)f2bfbits(f[6]) | ((unsigned)f2bfbits(f[7])<<16);
    return v;
}
__device__ __forceinline__ unsigned fmono(float v){
    unsigned u = __float_as_uint(v);
    return (u & 0x80000000u) ? ~u : (u | 0x80000000u);
}

// -------------------- zero stats --------------------
__global__ void zero_stats(float* s){ s[blockIdx.x*256 + threadIdx.x] = 0.0f; }

// -------------------- W26 = w2 @ w1  (256x6, stored [j][c]) --------------------
__global__ __launch_bounds__(256) void prep_w26(const float* __restrict__ w1,
                                                const float* __restrict__ w2,
                                                float* __restrict__ W26){
    int c = threadIdx.x;
    float acc[6] = {0,0,0,0,0,0};
    for (int k=0;k<256;k++){
        float w2v = w2[c*256+k];
        #pragma unroll
        for (int j=0;j<6;j++) acc[j] = fmaf(w2v, w1[k*6+j], acc[j]);
    }
    #pragma unroll
    for (int j=0;j<6;j++) W26[j*256+c] = acc[j];
}

// -------------------- FPS: 1 block/batch, 256 thr, 16 pts/thr -----------------
__global__ __launch_bounds__(256) void fps_kernel(const float* __restrict__ p,
                                                  int* __restrict__ idxc,
                                                  float* __restrict__ cntrd){
    __shared__ float px[N_], py[N_], pz[N_];
    __shared__ unsigned long long warr[2][4];
    const int b = blockIdx.x;
    const int t = threadIdx.x;
    const float* pb = p + (size_t)b*N_*3;
    float rx[16], ry[16], rz[16], dist[16];
    #pragma unroll
    for (int j=0;j<16;j++){
        int i = t*16+j;
        float x = pb[i*3+0];
        float y = pb[i*3+1];
        float z = pb[i*3+2];
        rx[j]=x; ry[j]=y; rz[j]=z;
        px[i]=x; py[i]=y; pz[i]=z;
        dist[j]=1e10f;
    }
    __syncthreads();
    int cur = 0;
    if (t==0){
        idxc[b*NS_] = 0;
        cntrd[(size_t)(b*NS_)*3+0] = px[0];
        cntrd[(size_t)(b*NS_)*3+1] = py[0];
        cntrd[(size_t)(b*NS_)*3+2] = pz[0];
    }
    const unsigned invbase = 0xFFFFFFFFu - (unsigned)(t*16);
    for (int s=1; s<NS_; s++){
        float cx = px[cur], cy = py[cur], cz = pz[cur];
        float best = -1.0f; int bj = 0;
        #pragma unroll
        for (int j=0;j<16;j++){
            float dx = __fsub_rn(rx[j],cx);
            float dy = __fsub_rn(ry[j],cy);
            float dz = __fsub_rn(rz[j],cz);
            float d  = __fadd_rn(__fadd_rn(__fmul_rn(dx,dx),__fmul_rn(dy,dy)),__fmul_rn(dz,dz));
            float dm = fminf(dist[j], d);
            dist[j] = dm;
            bool gt = dm > best;
            best = gt ? dm : best;
            bj   = gt ? j  : bj;
        }
        unsigned long long key = ((unsigned long long)__float_as_uint(best)<<32)
                               | (unsigned)(invbase - (unsigned)bj);
        #pragma unroll
        for (int m=1;m<64;m<<=1){
            unsigned long long o = __shfl_xor(key, m, 64);
            key = key > o ? key : o;
        }
        if ((t&63)==0) warr[s&1][t>>6] = key;
        __syncthreads();
        unsigned long long g = warr[s&1][0];
        #pragma unroll
        for (int w=1;w<4;w++){ unsigned long long o = warr[s&1][w]; g = g > o ? g : o; }
        cur = (int)(0xFFFFFFFFu - (unsigned)(g & 0xFFFFFFFFull));
        if (t==0){
            idxc[b*NS_+s] = cur;
            cntrd[(size_t)(b*NS_+s)*3+0] = px[cur];
            cntrd[(size_t)(b*NS_+s)*3+1] = py[cur];
            cntrd[(size_t)(b*NS_+s)*3+2] = pz[cur];
        }
    }
}

// -------------------- KNN: 1 block (256 thr) per centroid --------------------
__global__ __launch_bounds__(256) void knn_kernel(const float* __restrict__ p,
                                                  const int* __restrict__ idxc,
                                                  int* __restrict__ knn){
    __shared__ unsigned long long warr[4];
    const int bid = blockIdx.x;
    const int b = bid >> 10;
    const int t = threadIdx.x;
    const float* pb = p + (size_t)b*N_*3;
    const int ci = idxc[bid];
    float cx = pb[ci*3+0];
    float cy = pb[ci*3+1];
    float cz = pb[ci*3+2];
    float c2 = __fadd_rn(__fadd_rn(__fmul_rn(cx,cx),__fmul_rn(cy,cy)),__fmul_rn(cz,cz));
    float d2[16];
    const int base = t*16;
    #pragma unroll
    for (int j=0;j<16;j++){
        int i = base+j;
        float x = pb[i*3+0];
        float y = pb[i*3+1];
        float z = pb[i*3+2];
        float p2 = __fadd_rn(__fadd_rn(__fmul_rn(x,x),__fmul_rn(y,y)),__fmul_rn(z,z));
        float dot= __fadd_rn(__fadd_rn(__fmul_rn(cx,x),__fmul_rn(cy,y)),__fmul_rn(cz,z));
        d2[j] = __fsub_rn(__fadd_rn(c2,p2), __fmul_rn(2.0f,dot));
    }
    for (int it=0; it<KNN_; it++){
        unsigned long long best = ~0ull;
        #pragma unroll
        for (int j=0;j<16;j++){
            unsigned long long key = ((unsigned long long)fmono(d2[j])<<32) | (unsigned)(base+j);
            best = best < key ? best : key;
        }
        #pragma unroll
        for (int m=1;m<64;m<<=1){
            unsigned long long o = __shfl_xor(best, m, 64);
            best = best < o ? best : o;
        }
        if ((t&63)==0) warr[t>>6] = best;
        __syncthreads();
        unsigned long long g = warr[0];
        #pragma unroll
        for (int w=1;w<4;w++){ unsigned long long o = warr[w]; g = g < o ? g : o; }
        int idx = (int)(g & 0xFFFFFFFFull);
        if ((idx>>4)==t) d2[idx & 15] = INFINITY;
        if (t==0) knn[(size_t)bid*KNN_ + it] = idx;
        __syncthreads();
    }
}

// -------------------- gather + conv1 + conv2 (+b2) -> z2 bf16 [256][NPOS] ------
__global__ __launch_bounds__(256) void conv12_kernel(const float* __restrict__ p,
                                                     const float* __restrict__ f,
                                                     const int* __restrict__ knn,
                                                     const float* __restrict__ W26,
                                                     const float* __restrict__ b2,
                                                     bf16* __restrict__ z2){
    __shared__ float Ws[6][256];
    __shared__ float xs[6][32];
    const int bid = blockIdx.x;
    const int b = bid >> 10;
    const int t = threadIdx.x;
    #pragma unroll
    for (int r=0;r<6;r++) Ws[r][t] = W26[r*256+t];
    if (t < 32){
        int i = knn[(size_t)bid*KNN_ + t];
        const float* pb = p + (size_t)b*N_*3;
        const float* fb = f + (size_t)b*3*N_;
        xs[0][t] = pb[i*3+0];
        xs[1][t] = pb[i*3+1];
        xs[2][t] = pb[i*3+2];
        xs[3][t] = fb[0*N_+i];
        xs[4][t] = fb[1*N_+i];
        xs[5][t] = fb[2*N_+i];
    }
    __syncthreads();
    float w0=Ws[0][t], w1v=Ws[1][t], w2v=Ws[2][t], w3v=Ws[3][t], w4v=Ws[4][t], w5v=Ws[5][t];
    float bias = b2[t];
    bf16* zrow = z2 + (size_t)t*NPOS_ + (size_t)bid*KNN_;
    for (int k0=0;k0<32;k0+=8){
        float y[8];
        #pragma unroll
        for (int u=0;u<8;u++){
            int k = k0+u;
            float acc = bias;
            acc = fmaf(w0, xs[0][k], acc);
            acc = fmaf(w1v,xs[1][k], acc);
            acc = fmaf(w2v,xs[2][k], acc);
            acc = fmaf(w3v,xs[3][k], acc);
            acc = fmaf(w4v,xs[4][k], acc);
            acc = fmaf(w5v,xs[5][k], acc);
            y[u] = acc;
        }
        *reinterpret_cast<uint4*>(zrow + k0) = pack8(y);
    }
}

// -------------------- BN stats --------------------
__global__ __launch_bounds__(256) void stats_kernel(const bf16* __restrict__ z,
                                                    float* __restrict__ sums){
    __shared__ float sw[4], qw[4];
    const int c = blockIdx.y;
    const int chunk = blockIdx.x;
    const int t = threadIdx.x;
    const bf16* zp = z + (size_t)c*NPOS_ + (size_t)chunk*16384;
    const uint4* zp4 = reinterpret_cast<const uint4*>(zp);
    float s=0.f, q=0.f;
    for (int r=0;r<8;r++){
        uint4 v = zp4[r*256 + t];
        float fv[8]; unpack8(v, fv);
        #pragma unroll
        for (int u=0;u<8;u++){ s += fv[u]; q = fmaf(fv[u], fv[u], q); }
    }
    #pragma unroll
    for (int m=1;m<64;m<<=1){ s += __shfl_xor(s,m,64); q += __shfl_xor(q,m,64); }
    if ((t&63)==0){ sw[t>>6]=s; qw[t>>6]=q; }
    __syncthreads();
    if (t==0){
        s = sw[0]+sw[1]+sw[2]+sw[3];
        q = qw[0]+qw[1]+qw[2]+qw[3];
        atomicAdd(&sums[c*2+0], s);
        atomicAdd(&sums[c*2+1], q);
    }
}

// -------------------- BN normalize + ReLU in-place --------------------
__global__ __launch_bounds__(256) void norm_kernel(bf16* __restrict__ z,
                                                   const float* __restrict__ sums,
                                                   const float* __restrict__ g,
                                                   const float* __restrict__ be){
    const int c = blockIdx.y;
    const int chunk = blockIdx.x;
    const int t = threadIdx.x;
    const float inv = 1.0f/(float)NPOS_;
    float mean = sums[c*2+0]*inv;
    float var  = sums[c*2+1]*inv - mean*mean;
    float rs = rsqrtf(var + BN_EPS_);
    float a  = g[c]*rs;
    float bb = be[c] - mean*a;
    bf16* zp = z + (size_t)c*NPOS_ + (size_t)chunk*16384;
    uint4* zp4 = reinterpret_cast<uint4*>(zp);
    for (int r=0;r<8;r++){
        uint4 v = zp4[r*256 + t];
        float fv[8]; unpack8(v, fv);
        #pragma unroll
        for (int u=0;u<8;u++) fv[u] = fmaxf(fmaf(fv[u], a, bb), 0.0f);
        zp4[r*256 + t] = pack8(fv);
    }
}

// -------------------- xm = max over K --------------------
__global__ __launch_bounds__(256) void xm_kernel(const bf16* __restrict__ x2n,
                                                 bf16* __restrict__ xm){
    int gid = blockIdx.x*256 + threadIdx.x;
    int c = gid >> 12;
    int bs = gid & 4095;
    const uint4* xp = reinterpret_cast<const uint4*>(x2n + (size_t)c*NPOS_ + (size_t)bs*KNN_);
    float m = -INFINITY;
    #pragma unroll
    for (int r=0;r<4;r++){
        uint4 v = xp[r];
        float fv[8]; unpack8(v, fv);
        #pragma unroll
        for (int u=0;u<8;u++) m = fmaxf(m, fv[u]);
    }
    xm[(size_t)c*4096 + bs] = __float2bfloat16(m);
}

// -------------------- small fp32 GEMM (t3 only) --------------------
__global__ __launch_bounds__(256) void gemm128(const float* __restrict__ A, int lda, int aoff,
                                               const bf16* __restrict__ B,
                                               int M, int N, int K,
                                               float* __restrict__ Cf){
    __shared__ float As[16][128];
    __shared__ float Bs[16][128];
    const int tid = threadIdx.x;
    const int tx = tid & 15, ty = tid >> 4;
    const int m0 = blockIdx.y*128, n0 = blockIdx.x*128;
    float acc[8][8];
    #pragma unroll
    for (int i=0;i<8;i++)
        #pragma unroll
        for (int j=0;j<8;j++) acc[i][j]=0.f;
    const int arow = tid >> 1, akg = tid & 1;
    const int bkk = tid >> 4, bng = tid & 15;
    for (int k0=0;k0<K;k0+=16){
        const float* aptr = A + (size_t)(m0+arow)*lda + aoff + k0 + akg*8;
        float4 a0 = *reinterpret_cast<const float4*>(aptr);
        float4 a1 = *reinterpret_cast<const float4*>(aptr+4);
        As[akg*8+0][arow]=a0.x; As[akg*8+1][arow]=a0.y;
        As[akg*8+2][arow]=a0.z; As[akg*8+3][arow]=a0.w;
        As[akg*8+4][arow]=a1.x; As[akg*8+5][arow]=a1.y;
        As[akg*8+6][arow]=a1.z; As[akg*8+7][arow]=a1.w;
        uint4 bv = *reinterpret_cast<const uint4*>(B + (size_t)(k0+bkk)*N + n0 + bng*8);
        float bf[8]; unpack8(bv, bf);
        *reinterpret_cast<float4*>(&Bs[bkk][bng*8+0]) = make_float4(bf[0],bf[1],bf[2],bf[3]);
        *reinterpret_cast<float4*>(&Bs[bkk][bng*8+4]) = make_float4(bf[4],bf[5],bf[6],bf[7]);
        __syncthreads();
        #pragma unroll
        for (int kk=0;kk<16;kk++){
            float a[8], b[8];
            *reinterpret_cast<float4*>(&a[0]) = *reinterpret_cast<float4*>(&As[kk][ty*8+0]);
            *reinterpret_cast<float4*>(&a[4]) = *reinterpret_cast<float4*>(&As[kk][ty*8+4]);
            *reinterpret_cast<float4*>(&b[0]) = *reinterpret_cast<float4*>(&Bs[kk][tx*8+0]);
            *reinterpret_cast<float4*>(&b[4]) = *reinterpret_cast<float4*>(&Bs[kk][tx*8+4]);
            #pragma unroll
            for (int i=0;i<8;i++)
                #pragma unroll
                for (int j=0;j<8;j++)
                    acc[i][j] = fmaf(a[i], b[j], acc[i][j]);
        }
        __syncthreads();
    }
    const int n = n0 + tx*8;
    #pragma unroll
    for (int i=0;i<8;i++){
        int m = m0 + ty*8 + i;
        *reinterpret_cast<float4*>(Cf + (size_t)m*N + n + 0) = make_float4(acc[i][0],acc[i][1],acc[i][2],acc[i][3]);
        *reinterpret_cast<float4*>(Cf + (size_t)m*N + n + 4) = make_float4(acc[i][4],acc[i][5],acc[i][6],acc[i][7]);
    }
}

// -------------------- MFMA GEMM: out[m][n] = sum_k W[m][aoff+k]*act[k][n] -----
// W f32 (hi/lo bf16 split), act bf16 [K][NPOS], out bf16 [M][NPOS].
// Tile 128m x 128n, BK=32, 4 waves (2x2), 16x16x32 bf16 MFMA.
// t3 (nullable): out += t3[m][n>>5].
#define LDK 40   /* LDS row stride in bf16 elems: 80B = 20 banks, b128-aligned */
__global__ __launch_bounds__(256) void gemm_mfma(const float* __restrict__ W, int ldw, int aoff,
                                                 const bf16* __restrict__ act, int K,
                                                 bf16* __restrict__ out,
                                                 const float* __restrict__ t3){
    __shared__ __align__(16) unsigned short AsH[128*LDK];
    __shared__ __align__(16) unsigned short AsL[128*LDK];
    __shared__ __align__(16) unsigned short Bs [128*LDK];
    __shared__ float t3s[128][4];
    const unsigned short* actu = reinterpret_cast<const unsigned short*>(act);
    const int t = threadIdx.x;
    const int m0 = blockIdx.x*128, n0 = blockIdx.y*128;
    const int wave = t>>6, lane = t&63;
    const int wm = wave>>1, wn = wave&1;
    const int q = lane>>4, col = lane&15;

    if (t3 && t < 128){
        const float* src = t3 + (size_t)(m0+t)*4096 + (n0>>5);
        t3s[t][0]=src[0]; t3s[t][1]=src[1]; t3s[t][2]=src[2]; t3s[t][3]=src[3];
    }

    f32x4 acc[4][4];
    #pragma unroll
    for (int i=0;i<4;i++)
        #pragma unroll
        for (int j=0;j<4;j++) acc[i][j] = (f32x4){0.f,0.f,0.f,0.f};

    // staging coords
    const int ar = t>>1, ah = t&1;           // A: row, k-half
    const int bn = t&127, bh = t>>7;         // B: n-col, k-half

    for (int k0=0;k0<K;k0+=32){
        // ---- stage A (weights f32 -> hi/lo bf16) ----
        const float* aptr = W + (size_t)(m0+ar)*ldw + aoff + k0 + ah*16;
        float4 v[4];
        v[0]=*reinterpret_cast<const float4*>(aptr+0);
        v[1]=*reinterpret_cast<const float4*>(aptr+4);
        v[2]=*reinterpret_cast<const float4*>(aptr+8);
        v[3]=*reinterpret_cast<const float4*>(aptr+12);
        unsigned short hi[16], lo[16];
        #pragma unroll
        for (int i=0;i<4;i++){
            const float* fv = reinterpret_cast<const float*>(&v[i]);
            #pragma unroll
            for (int j=0;j<4;j++){
                float x = fv[j];
                unsigned short h = f2bfbits(x);
                hi[i*4+j] = h;
                lo[i*4+j] = f2bfbits(__fsub_rn(x, bits2f(h)));
            }
        }
        *reinterpret_cast<uint4*>(&AsH[ar*LDK + ah*16 + 0]) = *reinterpret_cast<uint4*>(&hi[0]);
        *reinterpret_cast<uint4*>(&AsH[ar*LDK + ah*16 + 8]) = *reinterpret_cast<uint4*>(&hi[8]);
        *reinterpret_cast<uint4*>(&AsL[ar*LDK + ah*16 + 0]) = *reinterpret_cast<uint4*>(&lo[0]);
        *reinterpret_cast<uint4*>(&AsL[ar*LDK + ah*16 + 8]) = *reinterpret_cast<uint4*>(&lo[8]);
        // ---- stage B (act bf16, coalesced u16 loads, transposed store) ----
        unsigned short bvals[16];
        #pragma unroll
        for (int j=0;j<16;j++)
            bvals[j] = actu[(size_t)(k0 + bh*16 + j)*NPOS_ + n0 + bn];
        *reinterpret_cast<uint4*>(&Bs[bn*LDK + bh*16 + 0]) = *reinterpret_cast<uint4*>(&bvals[0]);
        *reinterpret_cast<uint4*>(&Bs[bn*LDK + bh*16 + 8]) = *reinterpret_cast<uint4*>(&bvals[8]);
        __syncthreads();
        // ---- fragments + mfma ----
        short8 bf[4], afh[4], afl[4];
        #pragma unroll
        for (int tn=0;tn<4;tn++)
            bf[tn] = *reinterpret_cast<const short8*>(&Bs[(wn*64+tn*16+col)*LDK + q*8]);
        #pragma unroll
        for (int tm=0;tm<4;tm++){
            afh[tm] = *reinterpret_cast<const short8*>(&AsH[(wm*64+tm*16+col)*LDK + q*8]);
            afl[tm] = *reinterpret_cast<const short8*>(&AsL[(wm*64+tm*16+col)*LDK + q*8]);
        }
        #pragma unroll
        for (int tm=0;tm<4;tm++)
            #pragma unroll
            for (int tn=0;tn<4;tn++){
                acc[tm][tn] = __builtin_amdgcn_mfma_f32_16x16x32_bf16(afh[tm], bf[tn], acc[tm][tn], 0, 0, 0);
                acc[tm][tn] = __builtin_amdgcn_mfma_f32_16x16x32_bf16(afl[tm], bf[tn], acc[tm][tn], 0, 0, 0);
            }
        __syncthreads();
    }
    // ---- epilogue: D[m= q*4+r][n= col] per tile ----
    #pragma unroll
    for (int tm=0;tm<4;tm++){
        #pragma unroll
        for (int tn=0;tn<4;tn++){
            int n_l = wn*64 + tn*16 + col;
            #pragma unroll
            for (int r=0;r<4;r++){
                int m_l = wm*64 + tm*16 + q*4 + r;
                float vv = acc[tm][tn][r];
                if (t3) vv += t3s[m_l][n_l>>5];
                out[(size_t)(m0+m_l)*NPOS_ + n0 + n_l] = __float2bfloat16(vv);
            }
        }
    }
}

// -------------------- final: BN + ReLU + maxpool over K -> out (f32) ---------
__global__ __launch_bounds__(256) void final_kernel(const bf16* __restrict__ z4,
                                                    const float* __restrict__ sums,
                                                    const float* __restrict__ g,
                                                    const float* __restrict__ be,
                                                    float* __restrict__ out){
    int gid = blockIdx.x*256 + threadIdx.x;
    int s = gid & 1023;
    int c = (gid >> 10) & 255;
    int b = gid >> 18;
    int bsi = b*NS_ + s;
    const float inv = 1.0f/(float)NPOS_;
    float mean = sums[c*2+0]*inv;
    float var  = sums[c*2+1]*inv - mean*mean;
    float rs = rsqrtf(var + BN_EPS_);
    float a  = g[c]*rs;
    float bb = be[c] - mean*a;
    const uint4* zp = reinterpret_cast<const uint4*>(z4 + (size_t)c*NPOS_ + (size_t)bsi*KNN_);
    float m = -INFINITY;
    #pragma unroll
    for (int r=0;r<4;r++){
        uint4 v = zp[r];
        float fv[8]; unpack8(v, fv);
        #pragma unroll
        for (int u=0;u<8;u++) m = fmaxf(m, fmaf(fv[u], a, bb));
    }
    m = fmaxf(m, 0.0f);
    out[(size_t)(b*256 + c)*NS_ + s] = m;
}

extern "C" void kernel_launch(void* const* d_in, const int* in_sizes, int n_in,
                              void* d_out, int out_size, void* d_ws, size_t ws_size,
                              hipStream_t stream) {
    const float* p   = (const float*)d_in[0];
    const float* f   = (const float*)d_in[1];
    const float* w1  = (const float*)d_in[2];
    const float* w2  = (const float*)d_in[3];
    const float* b2  = (const float*)d_in[4];
    const float* g2  = (const float*)d_in[5];
    const float* be2 = (const float*)d_in[6];
    const float* w3  = (const float*)d_in[7];
    const float* g3  = (const float*)d_in[8];
    const float* be3 = (const float*)d_in[9];
    const float* w4  = (const float*)d_in[10];
    const float* g4  = (const float*)d_in[11];
    const float* be4 = (const float*)d_in[12];

    char* ws = (char*)d_ws;
    int*   idxc  = (int*)(ws + 0);
    int*   knn   = (int*)(ws + 16384);
    float* W26   = (float*)(ws + 540672);
    float* stats = (float*)(ws + 546816);
    float* t3    = (float*)(ws + 555008);
    bf16*  z2    = (bf16*)(ws + 8943616);     // 64 MB (reused as z4)
    bf16*  xm    = (bf16*)(ws + 76052480);    // 2 MB
    bf16*  z3    = (bf16*)(ws + 78149632);    // 128 MB
    bf16*  z4    = z2;

    float* out_cntrd = (float*)d_out;
    float* out_feat  = (float*)d_out + (size_t)B_*NS_*3;

    zero_stats<<<8, 256, 0, stream>>>(stats);
    prep_w26<<<1, 256, 0, stream>>>(w1, w2, W26);
    fps_kernel<<<B_, 256, 0, stream>>>(p, idxc, out_cntrd);
    knn_kernel<<<B_*NS_, 256, 0, stream>>>(p, idxc, knn);
    conv12_kernel<<<B_*NS_, 256, 0, stream>>>(p, f, knn, W26, b2, z2);
    stats_kernel<<<dim3(8,256), 256, 0, stream>>>(z2, stats);
    norm_kernel<<<dim3(8,256), 256, 0, stream>>>(z2, stats, g2, be2);
    xm_kernel<<<4096, 256, 0, stream>>>(z2, xm);
    // t3[o][bs] = w3[:, :256] @ xm   (small, fp32)
    gemm128<<<dim3(32,4), 256, 0, stream>>>(w3, 512, 0, xm, 512, 4096, 256, t3);
    // z3 = w3[:, 256:] @ x2n + t3(broadcast over k)   (MFMA)
    gemm_mfma<<<dim3(4,1024), 256, 0, stream>>>(w3, 512, 256, z2, 256, z3, t3);
    stats_kernel<<<dim3(8,512), 256, 0, stream>>>(z3, stats + 512);
    norm_kernel<<<dim3(8,512), 256, 0, stream>>>(z3, stats + 512, g3, be3);
    // z4 = w4 @ x3   (MFMA; z4 aliases z2)
    gemm_mfma<<<dim3(2,1024), 256, 0, stream>>>(w4, 512, 0, z3, 512, z4, nullptr);
    stats_kernel<<<dim3(8,256), 256, 0, stream>>>(z4, stats + 1536);
    final_kernel<<<4096, 256, 0, stream>>>(z4, stats + 1536, g4, be4, out_feat);
}